// Round 2
// baseline (1098.639 us; speedup 1.0000x reference)
//
#include <hip/hip_runtime.h>
#include <hip/hip_bf16.h>

#define EPS 1e-5f

typedef __bf16 bf16;
typedef __attribute__((ext_vector_type(8))) __bf16 bf16x8;
typedef __attribute__((ext_vector_type(4))) float f32x4;

__device__ __forceinline__ float relu_f(float x) { return x > 0.f ? x : 0.f; }

// ---------------- workspace layout (float units) ----------------
// y1: 512*24*38*38 = 17,743,872   (also reused later: A/Bv/xg alias this region)
// y2: 4,435,968  y3: 1,228,800  y4: 307,200
// stats: 4 layers * 48 (sum[24], sumsq[24])
// whl: 3 layers * 2(hi,lo) * 256*256 bf16 = 786,432 B = 196,608 float slots
#define OFF_Y1   0
#define OFF_Y2   17743872
#define OFF_Y3   22179840
#define OFF_Y4   23408640
#define OFF_ST   23715840
#define OFF_WHL  23716032
#define WS_FLOATS 23912640
// aliases inside y1 region (y1 dead after conv2):
#define OFF_A    0
#define OFF_BV   3276800
#define OFF_XG   6553600

// ---------------- prep: zero stats + split g_w2..4 into bf16 hi/lo ----------------
__global__ __launch_bounds__(256) void k_prep(const float* w2, const float* w3,
                                              const float* w4, bf16* whl, float* stats) {
    int idx = blockIdx.x * 256 + threadIdx.x;
    if (blockIdx.x == 0 && threadIdx.x < 192) stats[threadIdx.x] = 0.f;
    if (idx < 3 * 65536) {
        int l = idx >> 16, e = idx & 65535;
        const float* w = (l == 0) ? w2 : (l == 1) ? w3 : w4;
        float v = w[e];
        bf16 hi = (bf16)v;
        whl[l * 131072 + e] = hi;
        whl[l * 131072 + 65536 + e] = (bf16)(v - (float)hi);
    }
}

// ---------------- conv1: 3->24 ch, 75->38, stride2 pad1, +bias +relu ----------------
__global__ __launch_bounds__(256) void k_conv1(const float* img, const float* w,
                                               const float* bias, float* y1) {
    __shared__ float wl[648];
    __shared__ float bl[24];
    int tid = threadIdx.x;
    if (tid < 24) bl[tid] = bias[tid];
    for (int i = tid; i < 648; i += 256) wl[i] = w[i];
    __syncthreads();
    int idx = blockIdx.x * 256 + tid;      // 512*1444 exactly
    int b = idx / 1444, rem = idx % 1444;
    int oh = rem / 38, ow = rem % 38;
    float acc[24];
#pragma unroll
    for (int o = 0; o < 24; ++o) acc[o] = bl[o];
    for (int ic = 0; ic < 3; ++ic) {
        float patch[9];
#pragma unroll
        for (int kh = 0; kh < 3; ++kh) {
            int ih = oh * 2 - 1 + kh;
#pragma unroll
            for (int kw = 0; kw < 3; ++kw) {
                int iw = ow * 2 - 1 + kw;
                bool ok = (unsigned)ih < 75u && (unsigned)iw < 75u;
                patch[kh * 3 + kw] = ok ? img[((b * 3 + ic) * 75 + ih) * 75 + iw] : 0.f;
            }
        }
#pragma unroll
        for (int o = 0; o < 24; ++o) {
#pragma unroll
            for (int t = 0; t < 9; ++t) acc[o] += wl[(o * 3 + ic) * 9 + t] * patch[t];
        }
    }
#pragma unroll
    for (int o = 0; o < 24; ++o) y1[(b * 24 + o) * 1444 + rem] = relu_f(acc[o]);
}

// ---------------- per-channel sum/sumsq over [B, 24, HW] ----------------
__global__ __launch_bounds__(256) void k_stats(const float* y, float* stats, int HW, int NBC) {
    int c = blockIdx.x / NBC, sub = blockIdx.x % NBC;
    int tid = threadIdx.x;
    float s = 0.f, s2 = 0.f;
    for (int b = sub; b < 512; b += NBC)
        for (int i = tid; i < HW; i += 256) {
            float v = y[(b * 24 + c) * HW + i];
            s += v; s2 += v * v;
        }
#pragma unroll
    for (int o = 1; o < 64; o <<= 1) { s += __shfl_xor(s, o); s2 += __shfl_xor(s2, o); }
    __shared__ float rs[4], rs2[4];
    int wave = tid >> 6, lane = tid & 63;
    if (lane == 0) { rs[wave] = s; rs2[wave] = s2; }
    __syncthreads();
    if (tid == 0) {
        atomicAdd(&stats[c], rs[0] + rs[1] + rs[2] + rs[3]);
        atomicAdd(&stats[24 + c], rs2[0] + rs2[1] + rs2[2] + rs2[3]);
    }
}

// ---------------- conv2/3/4: 24->24 ch, stride2 pad1; BN of input folded into read ----------------
__global__ __launch_bounds__(256) void k_conv(const float* yin, const float* w,
                                              const float* bias, const float* stats,
                                              const float* bng, const float* bnb,
                                              float* yout, int Hin, int Hout, float invN,
                                              int total) {
    __shared__ float wl[5184], bl[24], sc[24], sh[24];
    int tid = threadIdx.x;
    if (tid < 24) {
        bl[tid] = bias[tid];
        float mu = stats[tid] * invN;
        float var = stats[24 + tid] * invN - mu * mu;
        float s = bng[tid] * rsqrtf(var + EPS);
        sc[tid] = s; sh[tid] = bnb[tid] - mu * s;
    }
    for (int i = tid; i < 5184; i += 256) wl[i] = w[i];
    __syncthreads();
    int idx = blockIdx.x * 256 + tid;
    if (idx >= total) return;
    int HWo = Hout * Hout;
    int b = idx / HWo, rem = idx % HWo;
    int oh = rem / Hout, ow = rem % Hout;
    float acc[24];
#pragma unroll
    for (int o = 0; o < 24; ++o) acc[o] = bl[o];
    for (int ic = 0; ic < 24; ++ic) {
        float patch[9];
        float scc = sc[ic], shc = sh[ic];
#pragma unroll
        for (int kh = 0; kh < 3; ++kh) {
            int ih = oh * 2 - 1 + kh;
#pragma unroll
            for (int kw = 0; kw < 3; ++kw) {
                int iw = ow * 2 - 1 + kw;
                bool ok = (unsigned)ih < (unsigned)Hin && (unsigned)iw < (unsigned)Hin;
                patch[kh * 3 + kw] = ok ? yin[((b * 24 + ic) * Hin + ih) * Hin + iw] * scc + shc : 0.f;
            }
        }
#pragma unroll
        for (int o = 0; o < 24; ++o) {
#pragma unroll
            for (int t = 0; t < 9; ++t) acc[o] += wl[(o * 24 + ic) * 9 + t] * patch[t];
        }
    }
#pragma unroll
    for (int o = 0; o < 24; ++o) yout[(b * 24 + o) * HWo + rem] = relu_f(acc[o]);
}

// ---------------- objects: bn4 + coords, project through split g_w1; also zero xg ----------------
__global__ __launch_bounds__(256) void k_obj(const float* y4, const float* qst,
                                             const float* w1, const float* b1,
                                             const float* stats, const float* bng,
                                             const float* bnb, float* A, float* Bv, float* xg) {
    int b = blockIdx.x, tid = threadIdx.x;
    __shared__ float sc[24], sh[24], obj[26], q[11];
    xg[b * 256 + tid] = 0.f;
    if (tid < 24) {
        float mu = stats[tid] * (1.f / 12800.f);
        float var = stats[24 + tid] * (1.f / 12800.f) - mu * mu;
        float s = bng[tid] * rsqrtf(var + EPS);
        sc[tid] = s; sh[tid] = bnb[tid] - mu * s;
    }
    if (tid < 11) q[tid] = qst[b * 11 + tid];
    __syncthreads();
    float wr[63];
#pragma unroll
    for (int k = 0; k < 63; ++k) wr[k] = w1[tid * 63 + k];
    float qdot = b1[tid];
#pragma unroll
    for (int j = 0; j < 11; ++j) qdot += wr[52 + j] * q[j];
    for (int p = 0; p < 25; ++p) {
        __syncthreads();
        if (tid < 24) obj[tid] = y4[(b * 24 + tid) * 25 + p] * sc[tid] + sh[tid];
        if (tid == 24) obj[24] = ((p / 5) - 2) * 0.5f;
        if (tid == 25) obj[25] = ((p % 5) - 2) * 0.5f;
        __syncthreads();
        float a = 0.f, bv = qdot;
#pragma unroll
        for (int k = 0; k < 26; ++k) { a += wr[k] * obj[k]; bv += wr[26 + k] * obj[k]; }
        A[(b * 25 + p) * 256 + tid] = a;
        Bv[(b * 25 + p) * 256 + tid] = bv;
    }
}

// ---------------- fused g-MLP: h1=relu(A_i+Bv_j); 3x [256x256 GEMM + bias + relu]; row-sum ----------------
// bf16 hi/lo split, 3 MFMA passes per tile (~fp32 accuracy). One h buffer in LDS.
__global__ __launch_bounds__(256, 2) void k_g(const float* A, const float* Bv, const bf16* whl,
                                              const float* gb2, const float* gb3,
                                              const float* gb4, float* xg) {
    __shared__ alignas(16) bf16 hHI[64 * 264];
    __shared__ alignas(16) bf16 hLO[64 * 264];
    __shared__ float biasL[3][256];
    int tid = threadIdx.x;
    int blk = blockIdx.x;
    int b = blk / 10, t = blk % 10;
    int r0 = t * 64;
    int rmax = 625 - r0; if (rmax > 64) rmax = 64;
    biasL[0][tid] = gb2[tid];
    biasL[1][tid] = gb3[tid];
    biasL[2][tid] = gb4[tid];
    const float* Ab = A + b * 25 * 256;
    const float* Bb = Bv + b * 25 * 256;
    for (int r = 0; r < 64; ++r) {
        int pr = r0 + r; if (pr > 624) pr = 624;   // clamp; masked at final sum
        int i = pr % 25, j = pr / 25;
        float v = relu_f(Ab[i * 256 + tid] + Bb[j * 256 + tid]);
        bf16 hi = (bf16)v;
        hHI[r * 264 + tid] = hi;
        hLO[r * 264 + tid] = (bf16)(v - (float)hi);
    }
    __syncthreads();
    int wave = tid >> 6, lane = tid & 63;
    int quad = lane >> 4, l15 = lane & 15;
    int colbase = wave * 64;
#pragma unroll 1
    for (int layer = 0; layer < 3; ++layer) {
        const bf16* Whi = whl + layer * 131072;
        const bf16* Wlo = Whi + 65536;
        f32x4 acc[4][4];
#pragma unroll
        for (int rt = 0; rt < 4; ++rt)
#pragma unroll
            for (int ct = 0; ct < 4; ++ct) acc[rt][ct] = (f32x4){0.f, 0.f, 0.f, 0.f};
#pragma unroll 2
        for (int ks = 0; ks < 8; ++ks) {
            int ko = ks * 32 + quad * 8;
            bf16x8 ahi[4], alo[4], bhi[4], blo[4];
#pragma unroll
            for (int rt = 0; rt < 4; ++rt) {
                int off = (rt * 16 + l15) * 264 + ko;
                ahi[rt] = *(const bf16x8*)&hHI[off];
                alo[rt] = *(const bf16x8*)&hLO[off];
            }
#pragma unroll
            for (int ct = 0; ct < 4; ++ct) {
                int c = colbase + ct * 16 + l15;
                bhi[ct] = *(const bf16x8*)&Whi[c * 256 + ko];
                blo[ct] = *(const bf16x8*)&Wlo[c * 256 + ko];
            }
#pragma unroll
            for (int rt = 0; rt < 4; ++rt)
#pragma unroll
                for (int ct = 0; ct < 4; ++ct) {
                    acc[rt][ct] = __builtin_amdgcn_mfma_f32_16x16x32_bf16(ahi[rt], bhi[ct], acc[rt][ct], 0, 0, 0);
                    acc[rt][ct] = __builtin_amdgcn_mfma_f32_16x16x32_bf16(ahi[rt], blo[ct], acc[rt][ct], 0, 0, 0);
                    acc[rt][ct] = __builtin_amdgcn_mfma_f32_16x16x32_bf16(alo[rt], bhi[ct], acc[rt][ct], 0, 0, 0);
                }
        }
        __syncthreads();   // all reads of h done; safe to overwrite
        if (layer < 2) {
#pragma unroll
            for (int rt = 0; rt < 4; ++rt)
#pragma unroll
                for (int ct = 0; ct < 4; ++ct) {
                    int c = colbase + ct * 16 + l15;
#pragma unroll
                    for (int v = 0; v < 4; ++v) {
                        int row = rt * 16 + quad * 4 + v;
                        float x = relu_f(acc[rt][ct][v] + biasL[layer][c]);
                        bf16 hi = (bf16)x;
                        hHI[row * 264 + c] = hi;
                        hLO[row * 264 + c] = (bf16)(x - (float)hi);
                    }
                }
            __syncthreads();
        } else {
#pragma unroll
            for (int ct = 0; ct < 4; ++ct) {
                int c = colbase + ct * 16 + l15;
                float s = 0.f;
#pragma unroll
                for (int rt = 0; rt < 4; ++rt)
#pragma unroll
                    for (int v = 0; v < 4; ++v) {
                        int row = rt * 16 + quad * 4 + v;
                        float x = relu_f(acc[rt][ct][v] + biasL[2][c]);
                        if (row < rmax) s += x;
                    }
                s += __shfl_xor(s, 16);
                s += __shfl_xor(s, 32);
                if (quad == 0) atomicAdd(&xg[b * 256 + c], s);
            }
        }
    }
}

// ---------------- f-MLP + log_softmax ----------------
__global__ __launch_bounds__(256) void k_f(const float* xg, const float* fw1, const float* fb1,
                                           const float* fw2, const float* fb2,
                                           const float* fw3, const float* fb3, float* out) {
    int b = blockIdx.x, tid = threadIdx.x;
    __shared__ float xb[256], h1[256], l10[10], red[1];
    xb[tid] = xg[b * 256 + tid];
    __syncthreads();
    float s = fb1[tid];
    {
        const float4* wr = (const float4*)&fw1[tid * 256];
        const float4* xv = (const float4*)xb;
#pragma unroll 8
        for (int k = 0; k < 64; ++k) {
            float4 w = wr[k], x = xv[k];
            s += w.x * x.x + w.y * x.y + w.z * x.z + w.w * x.w;
        }
    }
    h1[tid] = relu_f(s);
    __syncthreads();
    s = fb2[tid];
    {
        const float4* wr = (const float4*)&fw2[tid * 256];
        const float4* hv = (const float4*)h1;
#pragma unroll 8
        for (int k = 0; k < 64; ++k) {
            float4 w = wr[k], x = hv[k];
            s += w.x * x.x + w.y * x.y + w.z * x.z + w.w * x.w;
        }
    }
    __syncthreads();           // all reads of xb (layer1) finished before h1-sync
    xb[tid] = relu_f(s);       // xb now holds h2
    __syncthreads();
    if (tid < 10) {
        float v = fb3[tid];
        const float4* wr = (const float4*)&fw3[tid * 256];
        const float4* hv = (const float4*)xb;
#pragma unroll 8
        for (int k = 0; k < 64; ++k) {
            float4 w = wr[k], x = hv[k];
            v += w.x * x.x + w.y * x.y + w.z * x.z + w.w * x.w;
        }
        l10[tid] = v;
    }
    __syncthreads();
    if (tid == 0) {
        float m = l10[0];
        for (int i = 1; i < 10; ++i) m = fmaxf(m, l10[i]);
        float e = 0.f;
        for (int i = 0; i < 10; ++i) e += expf(l10[i] - m);
        red[0] = m + logf(e);
    }
    __syncthreads();
    if (tid < 10) out[b * 10 + tid] = l10[tid] - red[0];
}

extern "C" void kernel_launch(void* const* d_in, const int* in_sizes, int n_in,
                              void* d_out, int out_size, void* d_ws, size_t ws_size,
                              hipStream_t stream) {
    const float* img = (const float*)d_in[0];
    const float* qst = (const float*)d_in[1];
    const float* cw[4] = {(const float*)d_in[2], (const float*)d_in[6],
                          (const float*)d_in[10], (const float*)d_in[14]};
    const float* cb[4] = {(const float*)d_in[3], (const float*)d_in[7],
                          (const float*)d_in[11], (const float*)d_in[15]};
    const float* bg[4] = {(const float*)d_in[4], (const float*)d_in[8],
                          (const float*)d_in[12], (const float*)d_in[16]};
    const float* bb[4] = {(const float*)d_in[5], (const float*)d_in[9],
                          (const float*)d_in[13], (const float*)d_in[17]};
    const float* gw1 = (const float*)d_in[18];
    const float* gb1 = (const float*)d_in[19];
    const float* gw2 = (const float*)d_in[20];
    const float* gb2 = (const float*)d_in[21];
    const float* gw3 = (const float*)d_in[22];
    const float* gb3 = (const float*)d_in[23];
    const float* gw4 = (const float*)d_in[24];
    const float* gb4 = (const float*)d_in[25];
    const float* fw1 = (const float*)d_in[26];
    const float* fb1 = (const float*)d_in[27];
    const float* fw2 = (const float*)d_in[28];
    const float* fb2 = (const float*)d_in[29];
    const float* fw3 = (const float*)d_in[30];
    const float* fb3 = (const float*)d_in[31];

    float* ws = (float*)d_ws;
    float* y1 = ws + OFF_Y1;
    float* y2 = ws + OFF_Y2;
    float* y3 = ws + OFF_Y3;
    float* y4 = ws + OFF_Y4;
    float* stats = ws + OFF_ST;
    bf16* whl = (bf16*)(ws + OFF_WHL);
    float* A = ws + OFF_A;     // aliases y1 (dead after conv2)
    float* Bv = ws + OFF_BV;
    float* xg = ws + OFF_XG;
    float* out = (float*)d_out;

    k_prep<<<768, 256, 0, stream>>>(gw2, gw3, gw4, whl, stats);
    k_conv1<<<2888, 256, 0, stream>>>(img, cw[0], cb[0], y1);
    k_stats<<<24 * 16, 256, 0, stream>>>(y1, stats + 0, 1444, 16);
    k_conv<<<722, 256, 0, stream>>>(y1, cw[1], cb[1], stats + 0, bg[0], bb[0], y2,
                                    38, 19, 1.f / 739328.f, 184832);
    k_stats<<<24 * 16, 256, 0, stream>>>(y2, stats + 48, 361, 16);
    k_conv<<<200, 256, 0, stream>>>(y2, cw[2], cb[2], stats + 48, bg[1], bb[1], y3,
                                    19, 10, 1.f / 184832.f, 51200);
    k_stats<<<24 * 16, 256, 0, stream>>>(y3, stats + 96, 100, 16);
    k_conv<<<50, 256, 0, stream>>>(y3, cw[3], cb[3], stats + 96, bg[2], bb[2], y4,
                                   10, 5, 1.f / 51200.f, 12800);
    k_stats<<<24 * 16, 256, 0, stream>>>(y4, stats + 144, 25, 16);
    k_obj<<<512, 256, 0, stream>>>(y4, qst, gw1, gb1, stats + 144, bg[3], bb[3], A, Bv, xg);
    k_g<<<5120, 256, 0, stream>>>(A, Bv, whl, gb2, gb3, gb4, xg);
    k_f<<<512, 256, 0, stream>>>(xg, fw1, fb1, fw2, fb2, fw3, fb3, out);
}

// Round 3
// 859.583 us; speedup vs baseline: 1.2781x; 1.2781x over previous
//
#include <hip/hip_runtime.h>
#include <hip/hip_bf16.h>

#define EPS 1e-5f

typedef _Float16 half_t;
typedef __attribute__((ext_vector_type(8))) _Float16 h16x8;
typedef __attribute__((ext_vector_type(4))) _Float16 h16x4;
typedef __attribute__((ext_vector_type(4))) float f32x4;

__device__ __forceinline__ float relu_f(float x) { return x > 0.f ? x : 0.f; }

// ---------------- workspace layout (float units) ----------------
#define OFF_Y1   0
#define OFF_Y2   17743872
#define OFF_Y3   22179840
#define OFF_Y4   23408640
#define OFF_ST   23715840
#define OFF_WHL  23716032
#define WS_FLOATS 23912640
// aliases inside y1 region (y1 dead after conv2):
#define OFF_A    0
#define OFF_BV   3276800
#define OFF_XG   6553600

// ---------------- prep: zero stats + split g_w2..4 into f16 hi/lo, swizzled to b-frag order ----
// W'[cblk][ks][quad][l15][j] so a wave's b-frag load is lane-contiguous (1 KB/instr).
__global__ __launch_bounds__(256) void k_prep(const float* w2, const float* w3,
                                              const float* w4, half_t* whl, float* stats) {
    int idx = blockIdx.x * 256 + threadIdx.x;
    if (blockIdx.x == 0 && threadIdx.x < 192) stats[threadIdx.x] = 0.f;
    if (idx < 3 * 65536) {
        int l = idx >> 16, e = idx & 65535;
        const float* w = (l == 0) ? w2 : (l == 1) ? w3 : w4;
        float v = w[e];
        half_t hi = (half_t)v;
        half_t lo = (half_t)(v - (float)hi);
        int c = e >> 8, k = e & 255;
        int cblk = c >> 4, l15 = c & 15, ks = k >> 5, quad = (k >> 3) & 3, j = k & 7;
        int o = cblk * 4096 + ks * 512 + quad * 128 + l15 * 8 + j;
        whl[l * 131072 + o] = hi;
        whl[l * 131072 + 65536 + o] = lo;
    }
}

// ---------------- conv1: 3->24 ch, 75->38, stride2 pad1, +bias +relu ----------------
__global__ __launch_bounds__(256) void k_conv1(const float* img, const float* w,
                                               const float* bias, float* y1) {
    __shared__ float wl[648];
    __shared__ float bl[24];
    int tid = threadIdx.x;
    if (tid < 24) bl[tid] = bias[tid];
    for (int i = tid; i < 648; i += 256) wl[i] = w[i];
    __syncthreads();
    int idx = blockIdx.x * 256 + tid;      // 512*1444 exactly
    int b = idx / 1444, rem = idx % 1444;
    int oh = rem / 38, ow = rem % 38;
    float acc[24];
#pragma unroll
    for (int o = 0; o < 24; ++o) acc[o] = bl[o];
    for (int ic = 0; ic < 3; ++ic) {
        float patch[9];
#pragma unroll
        for (int kh = 0; kh < 3; ++kh) {
            int ih = oh * 2 - 1 + kh;
#pragma unroll
            for (int kw = 0; kw < 3; ++kw) {
                int iw = ow * 2 - 1 + kw;
                bool ok = (unsigned)ih < 75u && (unsigned)iw < 75u;
                patch[kh * 3 + kw] = ok ? img[((b * 3 + ic) * 75 + ih) * 75 + iw] : 0.f;
            }
        }
#pragma unroll
        for (int o = 0; o < 24; ++o) {
#pragma unroll
            for (int t = 0; t < 9; ++t) acc[o] += wl[(o * 3 + ic) * 9 + t] * patch[t];
        }
    }
#pragma unroll
    for (int o = 0; o < 24; ++o) y1[(b * 24 + o) * 1444 + rem] = relu_f(acc[o]);
}

// ---------------- per-channel sum/sumsq over [B, 24, HW] ----------------
__global__ __launch_bounds__(256) void k_stats(const float* y, float* stats, int HW, int NBC) {
    int c = blockIdx.x / NBC, sub = blockIdx.x % NBC;
    int tid = threadIdx.x;
    float s = 0.f, s2 = 0.f;
    for (int b = sub; b < 512; b += NBC)
        for (int i = tid; i < HW; i += 256) {
            float v = y[(b * 24 + c) * HW + i];
            s += v; s2 += v * v;
        }
#pragma unroll
    for (int o = 1; o < 64; o <<= 1) { s += __shfl_xor(s, o); s2 += __shfl_xor(s2, o); }
    __shared__ float rs[4], rs2[4];
    int wave = tid >> 6, lane = tid & 63;
    if (lane == 0) { rs[wave] = s; rs2[wave] = s2; }
    __syncthreads();
    if (tid == 0) {
        atomicAdd(&stats[c], rs[0] + rs[1] + rs[2] + rs[3]);
        atomicAdd(&stats[24 + c], rs2[0] + rs2[1] + rs2[2] + rs2[3]);
    }
}

// ---------------- conv2/3/4: 24->24 ch, stride2 pad1; BN of input folded into read ----------------
__global__ __launch_bounds__(256) void k_conv(const float* yin, const float* w,
                                              const float* bias, const float* stats,
                                              const float* bng, const float* bnb,
                                              float* yout, int Hin, int Hout, float invN,
                                              int total) {
    __shared__ float wl[5184], bl[24], sc[24], sh[24];
    int tid = threadIdx.x;
    if (tid < 24) {
        bl[tid] = bias[tid];
        float mu = stats[tid] * invN;
        float var = stats[24 + tid] * invN - mu * mu;
        float s = bng[tid] * rsqrtf(var + EPS);
        sc[tid] = s; sh[tid] = bnb[tid] - mu * s;
    }
    for (int i = tid; i < 5184; i += 256) wl[i] = w[i];
    __syncthreads();
    int idx = blockIdx.x * 256 + tid;
    if (idx >= total) return;
    int HWo = Hout * Hout;
    int b = idx / HWo, rem = idx % HWo;
    int oh = rem / Hout, ow = rem % Hout;
    float acc[24];
#pragma unroll
    for (int o = 0; o < 24; ++o) acc[o] = bl[o];
    for (int ic = 0; ic < 24; ++ic) {
        float patch[9];
        float scc = sc[ic], shc = sh[ic];
#pragma unroll
        for (int kh = 0; kh < 3; ++kh) {
            int ih = oh * 2 - 1 + kh;
#pragma unroll
            for (int kw = 0; kw < 3; ++kw) {
                int iw = ow * 2 - 1 + kw;
                bool ok = (unsigned)ih < (unsigned)Hin && (unsigned)iw < (unsigned)Hin;
                patch[kh * 3 + kw] = ok ? yin[((b * 24 + ic) * Hin + ih) * Hin + iw] * scc + shc : 0.f;
            }
        }
#pragma unroll
        for (int o = 0; o < 24; ++o) {
#pragma unroll
            for (int t = 0; t < 9; ++t) acc[o] += wl[(o * 24 + ic) * 9 + t] * patch[t];
        }
    }
#pragma unroll
    for (int o = 0; o < 24; ++o) yout[(b * 24 + o) * HWo + rem] = relu_f(acc[o]);
}

// ---------------- objects: bn4 + coords, project through split g_w1; also zero xg ----------------
__global__ __launch_bounds__(256) void k_obj(const float* y4, const float* qst,
                                             const float* w1, const float* b1,
                                             const float* stats, const float* bng,
                                             const float* bnb, float* A, float* Bv, float* xg) {
    int b = blockIdx.x, tid = threadIdx.x;
    __shared__ float w1l[16128];          // 256x63, staged coalesced
    __shared__ float sc[24], sh[24], obj[26], q[11];
    xg[b * 256 + tid] = 0.f;
    for (int i = tid; i < 16128; i += 256) w1l[i] = w1[i];
    if (tid < 24) {
        float mu = stats[tid] * (1.f / 12800.f);
        float var = stats[24 + tid] * (1.f / 12800.f) - mu * mu;
        float s = bng[tid] * rsqrtf(var + EPS);
        sc[tid] = s; sh[tid] = bnb[tid] - mu * s;
    }
    if (tid < 11) q[tid] = qst[b * 11 + tid];
    __syncthreads();
    float wr[63];
#pragma unroll
    for (int k = 0; k < 63; ++k) wr[k] = w1l[tid * 63 + k];
    float qdot = b1[tid];
#pragma unroll
    for (int j = 0; j < 11; ++j) qdot += wr[52 + j] * q[j];
    for (int p = 0; p < 25; ++p) {
        __syncthreads();
        if (tid < 24) obj[tid] = y4[(b * 24 + tid) * 25 + p] * sc[tid] + sh[tid];
        if (tid == 24) obj[24] = ((p / 5) - 2) * 0.5f;
        if (tid == 25) obj[25] = ((p % 5) - 2) * 0.5f;
        __syncthreads();
        float a = 0.f, bv = qdot;
#pragma unroll
        for (int k = 0; k < 26; ++k) { a += wr[k] * obj[k]; bv += wr[26 + k] * obj[k]; }
        A[(b * 25 + p) * 256 + tid] = a;
        Bv[(b * 25 + p) * 256 + tid] = bv;
    }
}

// ---------------- fused g-MLP: 512 threads / 8 waves, per-wave 4rt x 2ct ----------------
// f16 hi/lo split, 3 MFMA passes (~fp32). One h buffer in LDS; weights read pre-swizzled.
__global__ __launch_bounds__(512, 4) void k_g(const float* A, const float* Bv, const half_t* whl,
                                              const float* gb2, const float* gb3,
                                              const float* gb4, float* xg) {
    __shared__ alignas(16) half_t hHI[64 * 264];
    __shared__ alignas(16) half_t hLO[64 * 264];
    __shared__ float biasL[3][256];
    int tid = threadIdx.x;
    int blk = blockIdx.x;
    int b = blk / 10, t = blk % 10;
    int r0 = t * 64;
    int rmax = 625 - r0; if (rmax > 64) rmax = 64;
    if (tid < 256) { biasL[0][tid] = gb2[tid]; biasL[2][tid] = gb4[tid]; }
    else { biasL[1][tid - 256] = gb3[tid - 256]; }
    const float* Ab = A + b * 6400;
    const float* Bb = Bv + b * 6400;
#pragma unroll
    for (int it = 0; it < 8; ++it) {
        int e = it * 512 + tid;                 // 4096 float4-groups
        int r = e >> 6, c4 = (e & 63) << 2;
        int pr = r0 + r; if (pr > 624) pr = 624;   // clamp; masked at final sum
        int i = pr % 25, j = pr / 25;
        float4 av = *(const float4*)&Ab[i * 256 + c4];
        float4 bv = *(const float4*)&Bb[j * 256 + c4];
        float v0 = relu_f(av.x + bv.x), v1 = relu_f(av.y + bv.y);
        float v2 = relu_f(av.z + bv.z), v3 = relu_f(av.w + bv.w);
        h16x4 hi = {(half_t)v0, (half_t)v1, (half_t)v2, (half_t)v3};
        h16x4 lo = {(half_t)(v0 - (float)hi[0]), (half_t)(v1 - (float)hi[1]),
                    (half_t)(v2 - (float)hi[2]), (half_t)(v3 - (float)hi[3])};
        *(h16x4*)&hHI[r * 264 + c4] = hi;
        *(h16x4*)&hLO[r * 264 + c4] = lo;
    }
    __syncthreads();
    int wv = tid >> 6, lane = tid & 63;
    int quad = lane >> 4, l15 = lane & 15;
    int colbase = wv * 32;
#pragma unroll 1
    for (int layer = 0; layer < 3; ++layer) {
        const half_t* Whi = whl + layer * 131072;
        const half_t* Wlo = Whi + 65536;
        f32x4 acc[4][2];
#pragma unroll
        for (int rt = 0; rt < 4; ++rt)
#pragma unroll
            for (int ct = 0; ct < 2; ++ct) acc[rt][ct] = (f32x4){0.f, 0.f, 0.f, 0.f};
#pragma unroll 1
        for (int ks = 0; ks < 8; ++ks) {
            int ko = ks * 32 + quad * 8;
            h16x8 ahi[4], alo[4];
#pragma unroll
            for (int rt = 0; rt < 4; ++rt) {
                int off = (rt * 16 + l15) * 264 + ko;
                ahi[rt] = *(const h16x8*)&hHI[off];
                alo[rt] = *(const h16x8*)&hLO[off];
            }
#pragma unroll
            for (int ct = 0; ct < 2; ++ct) {
                int wo = (wv * 2 + ct) * 4096 + ks * 512 + lane * 8;   // pre-swizzled, lane-contiguous
                h16x8 bhi = *(const h16x8*)&Whi[wo];
                h16x8 blo = *(const h16x8*)&Wlo[wo];
#pragma unroll
                for (int rt = 0; rt < 4; ++rt) {
                    acc[rt][ct] = __builtin_amdgcn_mfma_f32_16x16x32_f16(ahi[rt], bhi, acc[rt][ct], 0, 0, 0);
                    acc[rt][ct] = __builtin_amdgcn_mfma_f32_16x16x32_f16(ahi[rt], blo, acc[rt][ct], 0, 0, 0);
                    acc[rt][ct] = __builtin_amdgcn_mfma_f32_16x16x32_f16(alo[rt], bhi, acc[rt][ct], 0, 0, 0);
                }
            }
        }
        __syncthreads();   // all reads of h done; safe to overwrite
        if (layer < 2) {
#pragma unroll
            for (int rt = 0; rt < 4; ++rt)
#pragma unroll
                for (int ct = 0; ct < 2; ++ct) {
                    int c = colbase + ct * 16 + l15;
#pragma unroll
                    for (int v = 0; v < 4; ++v) {
                        int row = rt * 16 + quad * 4 + v;
                        float x = relu_f(acc[rt][ct][v] + biasL[layer][c]);
                        half_t hi = (half_t)x;
                        hHI[row * 264 + c] = hi;
                        hLO[row * 264 + c] = (half_t)(x - (float)hi);
                    }
                }
            __syncthreads();
        } else {
#pragma unroll
            for (int ct = 0; ct < 2; ++ct) {
                int c = colbase + ct * 16 + l15;
                float s = 0.f;
#pragma unroll
                for (int rt = 0; rt < 4; ++rt)
#pragma unroll
                    for (int v = 0; v < 4; ++v) {
                        int row = rt * 16 + quad * 4 + v;
                        float x = relu_f(acc[rt][ct][v] + biasL[2][c]);
                        if (row < rmax) s += x;
                    }
                s += __shfl_xor(s, 16);
                s += __shfl_xor(s, 32);
                if (quad == 0) atomicAdd(&xg[b * 256 + c], s);
            }
        }
    }
}

// ---------------- f-MLP + log_softmax (2 batches per block: halves weight traffic) ------------
__global__ __launch_bounds__(256) void k_f(const float* xg, const float* fw1, const float* fb1,
                                           const float* fw2, const float* fb2,
                                           const float* fw3, const float* fb3, float* out) {
    int b0 = blockIdx.x * 2, tid = threadIdx.x;
    __shared__ float xb[2][256], h1[2][256], l10[2][10], red[2];
    xb[0][tid] = xg[b0 * 256 + tid];
    xb[1][tid] = xg[(b0 + 1) * 256 + tid];
    __syncthreads();
    float s0 = fb1[tid], s1 = s0;
    {
        const float4* wr = (const float4*)&fw1[tid * 256];
        const float4* x0 = (const float4*)xb[0];
        const float4* x1 = (const float4*)xb[1];
#pragma unroll 8
        for (int k = 0; k < 64; ++k) {
            float4 w = wr[k], a = x0[k], c = x1[k];
            s0 += w.x * a.x + w.y * a.y + w.z * a.z + w.w * a.w;
            s1 += w.x * c.x + w.y * c.y + w.z * c.z + w.w * c.w;
        }
    }
    h1[0][tid] = relu_f(s0);
    h1[1][tid] = relu_f(s1);
    __syncthreads();
    s0 = fb2[tid]; s1 = s0;
    {
        const float4* wr = (const float4*)&fw2[tid * 256];
        const float4* x0 = (const float4*)h1[0];
        const float4* x1 = (const float4*)h1[1];
#pragma unroll 8
        for (int k = 0; k < 64; ++k) {
            float4 w = wr[k], a = x0[k], c = x1[k];
            s0 += w.x * a.x + w.y * a.y + w.z * a.z + w.w * a.w;
            s1 += w.x * c.x + w.y * c.y + w.z * c.z + w.w * c.w;
        }
    }
    __syncthreads();
    xb[0][tid] = relu_f(s0);
    xb[1][tid] = relu_f(s1);
    __syncthreads();
    if (tid < 20) {
        int bb = tid / 10, o = tid % 10;
        float v = fb3[o];
        const float4* wr = (const float4*)&fw3[o * 256];
        const float4* hv = (const float4*)xb[bb];
#pragma unroll 8
        for (int k = 0; k < 64; ++k) {
            float4 w = wr[k], x = hv[k];
            v += w.x * x.x + w.y * x.y + w.z * x.z + w.w * x.w;
        }
        l10[bb][o] = v;
    }
    __syncthreads();
    if (tid < 2) {
        float m = l10[tid][0];
        for (int i = 1; i < 10; ++i) m = fmaxf(m, l10[tid][i]);
        float e = 0.f;
        for (int i = 0; i < 10; ++i) e += expf(l10[tid][i] - m);
        red[tid] = m + logf(e);
    }
    __syncthreads();
    if (tid < 20) {
        int bb = tid / 10, o = tid % 10;
        out[(b0 + bb) * 10 + o] = l10[bb][o] - red[bb];
    }
}

extern "C" void kernel_launch(void* const* d_in, const int* in_sizes, int n_in,
                              void* d_out, int out_size, void* d_ws, size_t ws_size,
                              hipStream_t stream) {
    const float* img = (const float*)d_in[0];
    const float* qst = (const float*)d_in[1];
    const float* cw[4] = {(const float*)d_in[2], (const float*)d_in[6],
                          (const float*)d_in[10], (const float*)d_in[14]};
    const float* cb[4] = {(const float*)d_in[3], (const float*)d_in[7],
                          (const float*)d_in[11], (const float*)d_in[15]};
    const float* bg[4] = {(const float*)d_in[4], (const float*)d_in[8],
                          (const float*)d_in[12], (const float*)d_in[16]};
    const float* bb[4] = {(const float*)d_in[5], (const float*)d_in[9],
                          (const float*)d_in[13], (const float*)d_in[17]};
    const float* gw1 = (const float*)d_in[18];
    const float* gb1 = (const float*)d_in[19];
    const float* gw2 = (const float*)d_in[20];
    const float* gb2 = (const float*)d_in[21];
    const float* gw3 = (const float*)d_in[22];
    const float* gb3 = (const float*)d_in[23];
    const float* gw4 = (const float*)d_in[24];
    const float* gb4 = (const float*)d_in[25];
    const float* fw1 = (const float*)d_in[26];
    const float* fb1 = (const float*)d_in[27];
    const float* fw2 = (const float*)d_in[28];
    const float* fb2 = (const float*)d_in[29];
    const float* fw3 = (const float*)d_in[30];
    const float* fb3 = (const float*)d_in[31];

    float* ws = (float*)d_ws;
    float* y1 = ws + OFF_Y1;
    float* y2 = ws + OFF_Y2;
    float* y3 = ws + OFF_Y3;
    float* y4 = ws + OFF_Y4;
    float* stats = ws + OFF_ST;
    half_t* whl = (half_t*)(ws + OFF_WHL);
    float* A = ws + OFF_A;     // aliases y1 (dead after conv2)
    float* Bv = ws + OFF_BV;
    float* xg = ws + OFF_XG;
    float* out = (float*)d_out;

    k_prep<<<768, 256, 0, stream>>>(gw2, gw3, gw4, whl, stats);
    k_conv1<<<2888, 256, 0, stream>>>(img, cw[0], cb[0], y1);
    k_stats<<<24 * 16, 256, 0, stream>>>(y1, stats + 0, 1444, 16);
    k_conv<<<722, 256, 0, stream>>>(y1, cw[1], cb[1], stats + 0, bg[0], bb[0], y2,
                                    38, 19, 1.f / 739328.f, 184832);
    k_stats<<<24 * 16, 256, 0, stream>>>(y2, stats + 48, 361, 16);
    k_conv<<<200, 256, 0, stream>>>(y2, cw[2], cb[2], stats + 48, bg[1], bb[1], y3,
                                    19, 10, 1.f / 184832.f, 51200);
    k_stats<<<24 * 16, 256, 0, stream>>>(y3, stats + 96, 100, 16);
    k_conv<<<50, 256, 0, stream>>>(y3, cw[3], cb[3], stats + 96, bg[2], bb[2], y4,
                                   10, 5, 1.f / 51200.f, 12800);
    k_stats<<<24 * 16, 256, 0, stream>>>(y4, stats + 144, 25, 16);
    k_obj<<<512, 256, 0, stream>>>(y4, qst, gw1, gb1, stats + 144, bg[3], bb[3], A, Bv, xg);
    k_g<<<5120, 512, 0, stream>>>(A, Bv, whl, gb2, gb3, gb4, xg);
    k_f<<<256, 256, 0, stream>>>(xg, fw1, fb1, fw2, fb2, fw3, fb3, out);
}

// Round 4
// 696.114 us; speedup vs baseline: 1.5782x; 1.2348x over previous
//
#include <hip/hip_runtime.h>
#include <hip/hip_bf16.h>

#define EPS 1e-5f

typedef _Float16 half_t;
typedef __attribute__((ext_vector_type(8))) _Float16 h16x8;
typedef __attribute__((ext_vector_type(4))) _Float16 h16x4;
typedef __attribute__((ext_vector_type(4))) float f32x4;

__device__ __forceinline__ float relu_f(float x) { return x > 0.f ? x : 0.f; }

// ---------------- workspace layout (float units) ----------------
// y1 512*24*38*38=17,743,872 | y2 4,435,968 | y3 1,228,800 | y4 307,200
// stats: 4 layers * 16 slots * 48 = 3072 | whl: 3*65536 f16 = 98,304 float slots
#define OFF_Y1   0
#define OFF_Y2   17743872
#define OFF_Y3   22179840
#define OFF_Y4   23408640
#define OFF_ST   23715840
#define OFF_WHL  23718912
// aliases inside y1 region (y1 dead after conv2):
#define OFF_A    0
#define OFF_BV   3276800
#define OFF_XG   6553600

// ---------------- prep: zero stats + cast g_w2..4 to f16, swizzled to A-frag lane order ----
// For W as MFMA A-operand: lane(quad,l15) reads W[c=mtile*16+l15][k=ks*32+quad*8+j], j=0..7.
// o = (mtile*8+ks)*512 + quad*128 + l15*8 + j  -> wave reads 1KB contiguous per (mtile,ks).
__global__ __launch_bounds__(256) void k_prep(const float* w2, const float* w3,
                                              const float* w4, half_t* whl, float* stats) {
    int idx = blockIdx.x * 256 + threadIdx.x;     // grid exact: 768*256 = 3*65536
    if (idx < 3072) stats[idx] = 0.f;
    int l = idx >> 16, e = idx & 65535;
    const float* w = (l == 0) ? w2 : (l == 1) ? w3 : w4;
    float v = w[e];
    int c = e >> 8, k = e & 255;
    int o = ((c >> 4) * 8 + (k >> 5)) * 512 + ((k >> 3) & 3) * 128 + (c & 15) * 8 + (k & 7);
    whl[l * 65536 + o] = (half_t)v;
}

// ---------------- conv1: 3->24 ch, 75->38, stride2 pad1, +bias +relu, fused out-stats ------
__global__ __launch_bounds__(256) void k_conv1(const float* img, const float* w,
                                               const float* bias, float* y1, float* ostats) {
    __shared__ float wl[648], bl[24], red[4][48];
    int tid = threadIdx.x;
    if (tid < 24) bl[tid] = bias[tid];
    for (int i = tid; i < 648; i += 256) wl[i] = w[i];
    __syncthreads();
    int idx = blockIdx.x * 256 + tid;      // 2888*256 = 512*1444 exact
    int b = idx / 1444, rem = idx % 1444;
    int oh = rem / 38, ow = rem % 38;
    float acc[24];
#pragma unroll
    for (int o = 0; o < 24; ++o) acc[o] = bl[o];
    for (int ic = 0; ic < 3; ++ic) {
        float patch[9];
#pragma unroll
        for (int kh = 0; kh < 3; ++kh) {
            int ih = oh * 2 - 1 + kh;
#pragma unroll
            for (int kw = 0; kw < 3; ++kw) {
                int iw = ow * 2 - 1 + kw;
                bool ok = (unsigned)ih < 75u && (unsigned)iw < 75u;
                patch[kh * 3 + kw] = ok ? img[((b * 3 + ic) * 75 + ih) * 75 + iw] : 0.f;
            }
        }
#pragma unroll
        for (int o = 0; o < 24; ++o)
#pragma unroll
            for (int t = 0; t < 9; ++t) acc[o] += wl[(o * 3 + ic) * 9 + t] * patch[t];
    }
    int wave = tid >> 6;
#pragma unroll
    for (int o = 0; o < 24; ++o) {
        acc[o] = relu_f(acc[o]);
        y1[(b * 24 + o) * 1444 + rem] = acc[o];
        float v = acc[o], v2 = v * v;
#pragma unroll
        for (int off = 1; off < 64; off <<= 1) { v += __shfl_xor(v, off); v2 += __shfl_xor(v2, off); }
        if ((tid & 63) == 0) { red[wave][o] = v; red[wave][24 + o] = v2; }
    }
    __syncthreads();
    if (tid < 48)
        atomicAdd(&ostats[(blockIdx.x & 15) * 48 + tid],
                  red[0][tid] + red[1][tid] + red[2][tid] + red[3][tid]);
}

// ---------------- conv2/3/4: 24->24, stride2 pad1; in-BN folded; fused out-stats ----------
__global__ __launch_bounds__(256) void k_conv(const float* yin, const float* w,
                                              const float* bias, const float* instats,
                                              const float* bng, const float* bnb,
                                              float* yout, float* ostats,
                                              int Hin, int Hout, float invN) {
    __shared__ float wl[5184], bl[24], sc[24], sh[24], red[4][48];
    int tid = threadIdx.x;
    if (tid < 24) {
        float s = 0.f, s2 = 0.f;
#pragma unroll
        for (int k = 0; k < 16; ++k) { s += instats[k * 48 + tid]; s2 += instats[k * 48 + 24 + tid]; }
        float mu = s * invN;
        float var = s2 * invN - mu * mu;
        float sca = bng[tid] * rsqrtf(var + EPS);
        sc[tid] = sca; sh[tid] = bnb[tid] - mu * sca;
        bl[tid] = bias[tid];
    }
    for (int i = tid; i < 5184; i += 256) wl[i] = w[i];
    __syncthreads();
    int idx = blockIdx.x * 256 + tid;      // grids exact for all three layers
    int HWo = Hout * Hout;
    int b = idx / HWo, rem = idx % HWo;
    int oh = rem / Hout, ow = rem % Hout;
    float acc[24];
#pragma unroll
    for (int o = 0; o < 24; ++o) acc[o] = bl[o];
    for (int ic = 0; ic < 24; ++ic) {
        float patch[9];
        float scc = sc[ic], shc = sh[ic];
#pragma unroll
        for (int kh = 0; kh < 3; ++kh) {
            int ih = oh * 2 - 1 + kh;
#pragma unroll
            for (int kw = 0; kw < 3; ++kw) {
                int iw = ow * 2 - 1 + kw;
                bool ok = (unsigned)ih < (unsigned)Hin && (unsigned)iw < (unsigned)Hin;
                patch[kh * 3 + kw] = ok ? yin[((b * 24 + ic) * Hin + ih) * Hin + iw] * scc + shc : 0.f;
            }
        }
#pragma unroll
        for (int o = 0; o < 24; ++o)
#pragma unroll
            for (int t = 0; t < 9; ++t) acc[o] += wl[(o * 24 + ic) * 9 + t] * patch[t];
    }
    int wave = tid >> 6;
#pragma unroll
    for (int o = 0; o < 24; ++o) {
        acc[o] = relu_f(acc[o]);
        yout[(b * 24 + o) * HWo + rem] = acc[o];
        float v = acc[o], v2 = v * v;
#pragma unroll
        for (int off = 1; off < 64; off <<= 1) { v += __shfl_xor(v, off); v2 += __shfl_xor(v2, off); }
        if ((tid & 63) == 0) { red[wave][o] = v; red[wave][24 + o] = v2; }
    }
    __syncthreads();
    if (tid < 48)
        atomicAdd(&ostats[(blockIdx.x & 15) * 48 + tid],
                  red[0][tid] + red[1][tid] + red[2][tid] + red[3][tid]);
}

// ---------------- objects: bn4 + coords once into LDS, project through split g_w1 ----------
__global__ __launch_bounds__(256) void k_obj(const float* y4, const float* qst,
                                             const float* w1, const float* b1,
                                             const float* instats, const float* bng,
                                             const float* bnb, float* A, float* Bv, float* xg) {
    int b = blockIdx.x, tid = threadIdx.x;
    __shared__ float w1l[16128];
    __shared__ float objs[25][28];
    __shared__ float sc[24], sh[24], q[11];
    xg[b * 256 + tid] = 0.f;
    for (int i = tid; i < 16128; i += 256) w1l[i] = w1[i];
    if (tid < 24) {
        float s = 0.f, s2 = 0.f;
#pragma unroll
        for (int k = 0; k < 16; ++k) { s += instats[k * 48 + tid]; s2 += instats[k * 48 + 24 + tid]; }
        float mu = s * (1.f / 12800.f);
        float var = s2 * (1.f / 12800.f) - mu * mu;
        float sca = bng[tid] * rsqrtf(var + EPS);
        sc[tid] = sca; sh[tid] = bnb[tid] - mu * sca;
    }
    if (tid < 11) q[tid] = qst[b * 11 + tid];
    __syncthreads();
    for (int i = tid; i < 600; i += 256) {
        int c = i / 25, p = i % 25;
        objs[p][c] = y4[b * 600 + i] * sc[c] + sh[c];
    }
    if (tid < 25) { objs[tid][24] = ((tid / 5) - 2) * 0.5f; objs[tid][25] = ((tid % 5) - 2) * 0.5f; }
    __syncthreads();
    float wr[63];
#pragma unroll
    for (int k = 0; k < 63; ++k) wr[k] = w1l[tid * 63 + k];
    float qdot = b1[tid];
#pragma unroll
    for (int j = 0; j < 11; ++j) qdot += wr[52 + j] * q[j];
#pragma unroll 1
    for (int p = 0; p < 25; ++p) {
        float a = 0.f, bv = qdot;
#pragma unroll
        for (int k = 0; k < 26; ++k) { a += wr[k] * objs[p][k]; bv += wr[26 + k] * objs[p][k]; }
        A[(b * 25 + p) * 256 + tid] = a;
        Bv[(b * 25 + p) * 256 + tid] = bv;
    }
}

// ---------------- fused g-MLP, single-pass f16, operand-swapped (W=A-op, h=B-op) ----------
// Per wave: 2 m-tiles (W rows) x 4 n-tiles (h rows). C/D: col(lane&15)=h-row, row(quad*4+v)=neuron.
// Mid-layer h-writes are h16x4 (4 consecutive neurons) -> ds_write_b64, row-major h intact.
__global__ __launch_bounds__(512, 6) void k_g(const float* A, const float* Bv, const half_t* whl,
                                              const float* gb2, const float* gb3,
                                              const float* gb4, float* xg) {
    __shared__ alignas(16) half_t h[64 * 264];
    __shared__ float biasL[3][256];
    int tid = threadIdx.x;
    int blk = blockIdx.x;
    int b = blk / 10, t = blk % 10;
    int r0 = t * 64;
    int rmax = 625 - r0; if (rmax > 64) rmax = 64;
    if (tid < 256) { biasL[0][tid] = gb2[tid]; biasL[2][tid] = gb4[tid]; }
    else biasL[1][tid - 256] = gb3[tid - 256];
    const float* Ab = A + b * 6400;
    const float* Bb = Bv + b * 6400;
#pragma unroll
    for (int it = 0; it < 8; ++it) {
        int e = it * 512 + tid;
        int r = e >> 6, c4 = (e & 63) << 2;
        int pr = r0 + r; if (pr > 624) pr = 624;   // clamp; masked at final sum
        int i = pr % 25, j = pr / 25;
        float4 av = *(const float4*)&Ab[i * 256 + c4];
        float4 bv = *(const float4*)&Bb[j * 256 + c4];
        h16x4 hv = {(half_t)relu_f(av.x + bv.x), (half_t)relu_f(av.y + bv.y),
                    (half_t)relu_f(av.z + bv.z), (half_t)relu_f(av.w + bv.w)};
        *(h16x4*)&h[r * 264 + c4] = hv;
    }
    __syncthreads();
    int wv = tid >> 6, lane = tid & 63;
    int quad = lane >> 4, l15 = lane & 15;
#pragma unroll 1
    for (int layer = 0; layer < 3; ++layer) {
        const half_t* W = whl + layer * 65536;
        f32x4 acc[2][4];
#pragma unroll
        for (int mi = 0; mi < 2; ++mi)
#pragma unroll
            for (int nt = 0; nt < 4; ++nt) acc[mi][nt] = (f32x4){0.f, 0.f, 0.f, 0.f};
#pragma unroll 2
        for (int ks = 0; ks < 8; ++ks) {
            int ko = ks * 32 + quad * 8;
            h16x8 bh[4];
#pragma unroll
            for (int nt = 0; nt < 4; ++nt)
                bh[nt] = *(const h16x8*)&h[(nt * 16 + l15) * 264 + ko];
            h16x8 aw[2];
#pragma unroll
            for (int mi = 0; mi < 2; ++mi)
                aw[mi] = *(const h16x8*)&W[((wv * 2 + mi) * 8 + ks) * 512 + lane * 8];
#pragma unroll
            for (int mi = 0; mi < 2; ++mi)
#pragma unroll
                for (int nt = 0; nt < 4; ++nt)
                    acc[mi][nt] = __builtin_amdgcn_mfma_f32_16x16x32_f16(aw[mi], bh[nt], acc[mi][nt], 0, 0, 0);
        }
        __syncthreads();   // all reads of h done; safe to overwrite
        if (layer < 2) {
#pragma unroll
            for (int mi = 0; mi < 2; ++mi) {
                int c0 = wv * 32 + mi * 16 + quad * 4;
#pragma unroll
                for (int nt = 0; nt < 4; ++nt) {
                    int row = nt * 16 + l15;
                    h16x4 hv;
#pragma unroll
                    for (int v = 0; v < 4; ++v)
                        hv[v] = (half_t)relu_f(acc[mi][nt][v] + biasL[layer][c0 + v]);
                    *(h16x4*)&h[row * 264 + c0] = hv;
                }
            }
            __syncthreads();
        } else {
#pragma unroll
            for (int mi = 0; mi < 2; ++mi) {
                int c0 = wv * 32 + mi * 16 + quad * 4;
#pragma unroll
                for (int v = 0; v < 4; ++v) {
                    float s = 0.f;
#pragma unroll
                    for (int nt = 0; nt < 4; ++nt) {
                        int row = nt * 16 + l15;
                        float x = relu_f(acc[mi][nt][v] + biasL[2][c0 + v]);
                        if (row < rmax) s += x;
                    }
                    s += __shfl_xor(s, 1);
                    s += __shfl_xor(s, 2);
                    s += __shfl_xor(s, 4);
                    s += __shfl_xor(s, 8);
                    if (l15 == 0) atomicAdd(&xg[b * 256 + c0 + v], s);
                }
            }
        }
    }
}

// ---------------- f-MLP + log_softmax (2 batches per block) ----------------
__global__ __launch_bounds__(256) void k_f(const float* xg, const float* fw1, const float* fb1,
                                           const float* fw2, const float* fb2,
                                           const float* fw3, const float* fb3, float* out) {
    int b0 = blockIdx.x * 2, tid = threadIdx.x;
    __shared__ float xb[2][256], h1[2][256], l10[2][10], red[2];
    xb[0][tid] = xg[b0 * 256 + tid];
    xb[1][tid] = xg[(b0 + 1) * 256 + tid];
    __syncthreads();
    float s0 = fb1[tid], s1 = s0;
    {
        const float4* wr = (const float4*)&fw1[tid * 256];
        const float4* x0 = (const float4*)xb[0];
        const float4* x1 = (const float4*)xb[1];
#pragma unroll 8
        for (int k = 0; k < 64; ++k) {
            float4 w = wr[k], a = x0[k], c = x1[k];
            s0 += w.x * a.x + w.y * a.y + w.z * a.z + w.w * a.w;
            s1 += w.x * c.x + w.y * c.y + w.z * c.z + w.w * c.w;
        }
    }
    h1[0][tid] = relu_f(s0);
    h1[1][tid] = relu_f(s1);
    __syncthreads();
    s0 = fb2[tid]; s1 = s0;
    {
        const float4* wr = (const float4*)&fw2[tid * 256];
        const float4* x0 = (const float4*)h1[0];
        const float4* x1 = (const float4*)h1[1];
#pragma unroll 8
        for (int k = 0; k < 64; ++k) {
            float4 w = wr[k], a = x0[k], c = x1[k];
            s0 += w.x * a.x + w.y * a.y + w.z * a.z + w.w * a.w;
            s1 += w.x * c.x + w.y * c.y + w.z * c.z + w.w * c.w;
        }
    }
    __syncthreads();
    xb[0][tid] = relu_f(s0);
    xb[1][tid] = relu_f(s1);
    __syncthreads();
    if (tid < 20) {
        int bb = tid / 10, o = tid % 10;
        float v = fb3[o];
        const float4* wr = (const float4*)&fw3[o * 256];
        const float4* hv = (const float4*)xb[bb];
#pragma unroll 8
        for (int k = 0; k < 64; ++k) {
            float4 w = wr[k], x = hv[k];
            v += w.x * x.x + w.y * x.y + w.z * x.z + w.w * x.w;
        }
        l10[bb][o] = v;
    }
    __syncthreads();
    if (tid < 2) {
        float m = l10[tid][0];
        for (int i = 1; i < 10; ++i) m = fmaxf(m, l10[tid][i]);
        float e = 0.f;
        for (int i = 0; i < 10; ++i) e += expf(l10[tid][i] - m);
        red[tid] = m + logf(e);
    }
    __syncthreads();
    if (tid < 20) {
        int bb = tid / 10, o = tid % 10;
        out[(b0 + bb) * 10 + o] = l10[bb][o] - red[bb];
    }
}

extern "C" void kernel_launch(void* const* d_in, const int* in_sizes, int n_in,
                              void* d_out, int out_size, void* d_ws, size_t ws_size,
                              hipStream_t stream) {
    const float* img = (const float*)d_in[0];
    const float* qst = (const float*)d_in[1];
    const float* cw[4] = {(const float*)d_in[2], (const float*)d_in[6],
                          (const float*)d_in[10], (const float*)d_in[14]};
    const float* cb[4] = {(const float*)d_in[3], (const float*)d_in[7],
                          (const float*)d_in[11], (const float*)d_in[15]};
    const float* bg[4] = {(const float*)d_in[4], (const float*)d_in[8],
                          (const float*)d_in[12], (const float*)d_in[16]};
    const float* bb[4] = {(const float*)d_in[5], (const float*)d_in[9],
                          (const float*)d_in[13], (const float*)d_in[17]};
    const float* gw1 = (const float*)d_in[18];
    const float* gb1 = (const float*)d_in[19];
    const float* gw2 = (const float*)d_in[20];
    const float* gb2 = (const float*)d_in[21];
    const float* gw3 = (const float*)d_in[22];
    const float* gb3 = (const float*)d_in[23];
    const float* gw4 = (const float*)d_in[24];
    const float* gb4 = (const float*)d_in[25];
    const float* fw1 = (const float*)d_in[26];
    const float* fb1 = (const float*)d_in[27];
    const float* fw2 = (const float*)d_in[28];
    const float* fb2 = (const float*)d_in[29];
    const float* fw3 = (const float*)d_in[30];
    const float* fb3 = (const float*)d_in[31];

    float* ws = (float*)d_ws;
    float* y1 = ws + OFF_Y1;
    float* y2 = ws + OFF_Y2;
    float* y3 = ws + OFF_Y3;
    float* y4 = ws + OFF_Y4;
    float* st = ws + OFF_ST;            // 4 layers * 16 slots * 48
    half_t* whl = (half_t*)(ws + OFF_WHL);
    float* A = ws + OFF_A;              // aliases y1 (dead after conv2)
    float* Bv = ws + OFF_BV;
    float* xg = ws + OFF_XG;
    float* out = (float*)d_out;

    k_prep<<<768, 256, 0, stream>>>(gw2, gw3, gw4, whl, st);
    k_conv1<<<2888, 256, 0, stream>>>(img, cw[0], cb[0], y1, st + 0 * 768);
    k_conv<<<722, 256, 0, stream>>>(y1, cw[1], cb[1], st + 0 * 768, bg[0], bb[0], y2,
                                    st + 1 * 768, 38, 19, 1.f / 739328.f);
    k_conv<<<200, 256, 0, stream>>>(y2, cw[2], cb[2], st + 1 * 768, bg[1], bb[1], y3,
                                    st + 2 * 768, 19, 10, 1.f / 184832.f);
    k_conv<<<50, 256, 0, stream>>>(y3, cw[3], cb[3], st + 2 * 768, bg[2], bb[2], y4,
                                   st + 3 * 768, 10, 5, 1.f / 51200.f);
    k_obj<<<512, 256, 0, stream>>>(y4, qst, gw1, gb1, st + 3 * 768, bg[3], bb[3], A, Bv, xg);
    k_g<<<5120, 512, 0, stream>>>(A, Bv, whl, gb2, gb3, gb4, xg);
    k_f<<<256, 256, 0, stream>>>(xg, fw1, fb1, fw2, fb2, fw3, fb3, out);
}